// Round 4
// baseline (403.585 us; speedup 1.0000x reference)
//
#include <hip/hip_runtime.h>
#include <math.h>

#define T 1024
#define C 192
#define LN_EPS 1e-5f

typedef __attribute__((ext_vector_type(4))) float f32x4;
typedef __attribute__((ext_vector_type(8))) __bf16 bf16x8;

__device__ __forceinline__ float silu_f(float x){ return x / (1.0f + __expf(-x)); }
__device__ __forceinline__ float wred_max(float v){
    #pragma unroll
    for(int o=32;o;o>>=1) v = fmaxf(v, __shfl_xor(v,o));
    return v;
}
__device__ __forceinline__ float wred_sum(float v){
    #pragma unroll
    for(int o=32;o;o>>=1) v += __shfl_xor(v,o);
    return v;
}

// ---------------- kernel 0: inclusive scan of durations ----------------
__global__ void k_scan(const int* __restrict__ d, float* __restrict__ Sd, float* __restrict__ Ed){
    __shared__ int s[T];
    int tid = threadIdx.x;
    int v = d[tid];
    s[tid] = v;
    for(int off=1; off<T; off<<=1){
        __syncthreads();
        int add = (tid>=off) ? s[tid-off] : 0;
        __syncthreads();
        s[tid] += add;
    }
    __syncthreads();
    Ed[tid] = (float)s[tid];
    Sd[tid] = (float)(s[tid]-v);
}

// ---------------- kernel 1: x = silu(H^T W_in + b_in) [T][C], 16 t per block ----------------
__global__ void k_proj_in(const float* __restrict__ H, const float* __restrict__ W_in,
                          const float* __restrict__ b_in, float* __restrict__ x){
    __shared__ float Hs[192*16];
    int tid = threadIdx.x;          // 192 threads
    int t0 = blockIdx.x*16;
    for(int idx=tid; idx<192*16; idx+=192){
        int ci = idx>>4, j = idx&15;
        Hs[idx] = H[ci*T + t0 + j];
    }
    __syncthreads();
    int c = tid;
    float acc[16];
    float bb = b_in[c];
    #pragma unroll
    for(int j=0;j<16;j++) acc[j] = bb;
    for(int ci=0; ci<192; ci++){
        float wv = W_in[ci*C + c];
        #pragma unroll
        for(int j4=0;j4<4;j4++){
            float4 h4 = *(const float4*)&Hs[ci*16 + j4*4];
            acc[j4*4+0] += h4.x*wv;
            acc[j4*4+1] += h4.y*wv;
            acc[j4*4+2] += h4.z*wv;
            acc[j4*4+3] += h4.w*wv;
        }
    }
    #pragma unroll
    for(int j=0;j<16;j++) x[(t0+j)*C + c] = silu_f(acc[j]);
}

// ---------------- kernel 2: conv1d(C->8,k3,p1) + LN(8) + SiLU -> xf [T][8] ----------------
__global__ void k_conv_ln(const float* __restrict__ x, const float* __restrict__ conv_w,
                          const float* __restrict__ conv_b, const float* __restrict__ gamma,
                          const float* __restrict__ beta, float* __restrict__ xf){
    __shared__ float xc[32][8];
    int tid = threadIdx.x;          // 256 = 32 t x 8 f
    int tl = tid >> 3, f = tid & 7;
    int t = blockIdx.x*32 + tl;
    float acc = conv_b[f];
    for(int k=0;k<3;k++){
        int tt = t + k - 1;
        if(tt>=0 && tt<T){
            const float* xr = x + tt*C;
            const float* wr = conv_w + f*C*3 + k;   // conv_w[f][c][k]
            for(int c2=0;c2<C;c2++) acc += xr[c2]*wr[c2*3];
        }
    }
    xc[tl][f] = acc;
    __syncthreads();
    float mu=0.f;
    #pragma unroll
    for(int j=0;j<8;j++) mu += xc[tl][j];
    mu *= 0.125f;
    float var=0.f;
    #pragma unroll
    for(int j=0;j<8;j++){ float dd = xc[tl][j]-mu; var += dd*dd; }
    var *= 0.125f;
    float vi = rsqrtf(var + LN_EPS);
    float v = (acc - mu)*vi*gamma[f] + beta[f];
    xf[t*8+f] = silu_f(v);
}

// ---------------- kernel 3: A1/A2 [t][12] = m-independent first-layer preacts; uv ----------------
__global__ void k_A(const float* __restrict__ Sd, const float* __restrict__ Ed,
                    const float* __restrict__ xf,
                    const float* __restrict__ wp1, const float* __restrict__ bp1,
                    const float* __restrict__ wc1, const float* __restrict__ bc1,
                    float* __restrict__ A1, float* __restrict__ A2, float* __restrict__ uv){
    int b = blockIdx.x, tid = threadIdx.x;
    if(b==4){
        if(tid<10){
            uv[tid]    = wp1[tid] - wp1[10+tid];   // u = wp1[0,:]-wp1[1,:]
            uv[10+tid] = wc1[tid] - wc1[10+tid];   // v = wc1[0,:]-wc1[1,:]
        }
        return;
    }
    int t = b*256 + tid;
    float sd = Sd[t], ed = Ed[t];
    float xv[8];
    #pragma unroll
    for(int k=0;k<8;k++) xv[k] = xf[t*8+k];
    #pragma unroll
    for(int j=0;j<10;j++){
        float a1 = bp1[j] - sd*wp1[j] + ed*wp1[10+j];
        float a2 = bc1[j] - sd*wc1[j] + ed*wc1[10+j];
        #pragma unroll
        for(int k=0;k<8;k++){
            a1 += xv[k]*wp1[(2+k)*10+j];
            a2 += xv[k]*wc1[(2+k)*10+j];
        }
        A1[t*12+j] = a1;
        A2[t*12+j] = a2;
    }
    A1[t*12+10]=0.f; A1[t*12+11]=0.f;
    A2[t*12+10]=0.f; A2[t*12+11]=0.f;
}

// ---------------- kernel 4: Hb = bf16(H) [192][1024] ----------------
__global__ void k_hb(const float* __restrict__ H, __bf16* __restrict__ Hb){
    int base = (blockIdx.x*256 + threadIdx.x)*8;
    float4 a = *(const float4*)(H + base);
    float4 b = *(const float4*)(H + base + 4);
    bf16x8 o;
    o[0]=(__bf16)a.x; o[1]=(__bf16)a.y; o[2]=(__bf16)a.z; o[3]=(__bf16)a.w;
    o[4]=(__bf16)b.x; o[5]=(__bf16)b.y; o[6]=(__bf16)b.z; o[7]=(__bf16)b.w;
    *(bf16x8*)(Hb + base) = o;
}

// ---------------- kernel 5: fold W_out -> WfoldT[c][800] bf16 (k = q*192+h | 768+q*2+p | pad0), b2 ----------------
__global__ void k_fold(const float* __restrict__ W_WH, const float* __restrict__ W_WC,
                       const float* __restrict__ b_WH, const float* __restrict__ b_WC,
                       const float* __restrict__ W_out, const float* __restrict__ b_out,
                       __bf16* __restrict__ WfT, float* __restrict__ b2){
    int i = blockIdx.x, c = threadIdx.x;     // 192 threads
    if(i < 768){
        float a = 0.f;
        for(int j=0;j<C;j++) a += W_WH[i*C+j]*W_out[j*C+c];
        WfT[c*800 + i] = (__bf16)a;
    } else if(i < 776){
        int r = i-768;
        float a = 0.f;
        for(int j=0;j<C;j++) a += W_WC[r*C+j]*W_out[j*C+c];
        WfT[c*800 + 768 + r] = (__bf16)a;
    } else if(i == 776){
        float a = b_out[c];
        for(int j=0;j<C;j++) a += (b_WH[j]+b_WC[j])*W_out[j*C+c];
        b2[c] = a;
    } else {
        for(int k=c; k<192*24; k+=192){
            int cc = k/24, j = k - (k/24)*24;
            WfT[cc*800 + 776 + j] = (__bf16)0.f;
        }
    }
}

// ---------------- kernel 6: main — 4 frames/block, 256 threads, MFMA pass2+epilogue ----------------
__global__ void __launch_bounds__(256, 4)
k_main(const __bf16* __restrict__ Hb, const float* __restrict__ A1, const float* __restrict__ A2,
       const float* __restrict__ uv,
       const float* __restrict__ wp2, const float* __restrict__ bp2,
       const float* __restrict__ wc2, const float* __restrict__ bc2,
       const __bf16* __restrict__ WfT, const float* __restrict__ b2g,
       float* __restrict__ out, int M)
{
    // LDS layout: PTlb [4*832] bf16 | wT [16*1024] bf16 | scr 288 f | wsm 96 f  = 40960 B
    __shared__ __align__(16) unsigned char smem[40960];
    __bf16* PTlb = (__bf16*)smem;                       // 6656 B
    __bf16* wT   = (__bf16*)(smem + 6656);              // 32768 B
    float*  scr  = (float*)(smem + 6656 + 32768);       // 288 floats
    float*  wsm  = scr + 288;                           // 96 floats

    int tid = threadIdx.x;
    int w = tid >> 6, lane = tid & 63;
    int m0 = blockIdx.x*4;
    float fis[4] = {(float)(m0+1),(float)(m0+2),(float)(m0+3),(float)(m0+4)};

    if(tid < 40)      wsm[tid] = wp2[tid];
    else if(tid < 44) wsm[tid] = bp2[tid-40];
    else if(tid < 64) wsm[tid] = wc2[tid-44];
    else if(tid < 66) wsm[tid] = bc2[tid-64];
    else if(tid < 86) wsm[tid] = uv[tid-66];
    if(tid >= 128 && tid < 224){        // zero-pad PTlb[m][776..800)
        int j = tid - 128;
        int mi = j/24, k = 776 + (j - (j/24)*24);
        PTlb[mi*832 + (k ^ ((mi&7)<<3))] = (__bf16)0.f;
    }
    __syncthreads();

    // ---- phase 1a: logits, track max only ----
    float pmax[4][4];
    #pragma unroll
    for(int mi=0;mi<4;mi++){
        #pragma unroll
        for(int q=0;q<4;q++) pmax[mi][q] = -3.0e38f;
    }
    #pragma unroll
    for(int ti=0;ti<4;ti++){
        int t = tid + ti*256;
        float4 a0 = *(const float4*)(A1 + t*12);
        float4 a1 = *(const float4*)(A1 + t*12 + 4);
        float4 a2 = *(const float4*)(A1 + t*12 + 8);
        float Av[10] = {a0.x,a0.y,a0.z,a0.w,a1.x,a1.y,a1.z,a1.w,a2.x,a2.y};
        #pragma unroll
        for(int mi=0;mi<4;mi++){
            float fi = fis[mi];
            float l0=wsm[40], l1=wsm[41], l2=wsm[42], l3=wsm[43];
            #pragma unroll
            for(int j=0;j<10;j++){
                float h = silu_f(Av[j] + fi*wsm[66+j]);
                l0 += h*wsm[j*4+0]; l1 += h*wsm[j*4+1];
                l2 += h*wsm[j*4+2]; l3 += h*wsm[j*4+3];
            }
            pmax[mi][0]=fmaxf(pmax[mi][0],l0); pmax[mi][1]=fmaxf(pmax[mi][1],l1);
            pmax[mi][2]=fmaxf(pmax[mi][2],l2); pmax[mi][3]=fmaxf(pmax[mi][3],l3);
        }
    }
    #pragma unroll
    for(int mi=0;mi<4;mi++){
        #pragma unroll
        for(int q=0;q<4;q++) pmax[mi][q] = wred_max(pmax[mi][q]);
    }
    if(lane==0){
        #pragma unroll
        for(int mi=0;mi<4;mi++){
            #pragma unroll
            for(int q=0;q<4;q++) scr[w*16 + mi*4 + q] = pmax[mi][q];
        }
    }
    __syncthreads();
    float mx[4][4];
    #pragma unroll
    for(int mi=0;mi<4;mi++){
        #pragma unroll
        for(int q=0;q<4;q++){
            float a = fmaxf(scr[0*16+mi*4+q], scr[1*16+mi*4+q]);
            float b = fmaxf(scr[2*16+mi*4+q], scr[3*16+mi*4+q]);
            mx[mi][q] = fmaxf(a,b);
        }
    }

    // ---- phase 1b: recompute logits, exp -> wT (bf16, swizzled); C-path; sums ----
    float sp[4][4], wcp[4][4][2];
    #pragma unroll
    for(int mi=0;mi<4;mi++){
        #pragma unroll
        for(int q=0;q<4;q++){ sp[mi][q]=0.f; wcp[mi][q][0]=0.f; wcp[mi][q][1]=0.f; }
    }
    #pragma unroll
    for(int ti=0;ti<4;ti++){
        int t = tid + ti*256;
        float4 a0 = *(const float4*)(A1 + t*12);
        float4 a1 = *(const float4*)(A1 + t*12 + 4);
        float4 a2 = *(const float4*)(A1 + t*12 + 8);
        float Av[10] = {a0.x,a0.y,a0.z,a0.w,a1.x,a1.y,a1.z,a1.w,a2.x,a2.y};
        float4 b0 = *(const float4*)(A2 + t*12);
        float4 b1 = *(const float4*)(A2 + t*12 + 4);
        float4 b2v = *(const float4*)(A2 + t*12 + 8);
        float Bv[10] = {b0.x,b0.y,b0.z,b0.w,b1.x,b1.y,b1.z,b1.w,b2v.x,b2v.y};
        #pragma unroll
        for(int mi=0;mi<4;mi++){
            float fi = fis[mi];
            float l0=wsm[40], l1=wsm[41], l2=wsm[42], l3=wsm[43];
            #pragma unroll
            for(int j=0;j<10;j++){
                float h = silu_f(Av[j] + fi*wsm[66+j]);
                l0 += h*wsm[j*4+0]; l1 += h*wsm[j*4+1];
                l2 += h*wsm[j*4+2]; l3 += h*wsm[j*4+3];
            }
            float e0 = __expf(l0 - mx[mi][0]);
            float e1 = __expf(l1 - mx[mi][1]);
            float e2 = __expf(l2 - mx[mi][2]);
            float e3 = __expf(l3 - mx[mi][3]);
            {
                int r0 = mi*4;
                wT[(r0+0)*1024 + (t ^ (((r0+0)&7)<<3))] = (__bf16)e0;
                wT[(r0+1)*1024 + (t ^ (((r0+1)&7)<<3))] = (__bf16)e1;
                wT[(r0+2)*1024 + (t ^ (((r0+2)&7)<<3))] = (__bf16)e2;
                wT[(r0+3)*1024 + (t ^ (((r0+3)&7)<<3))] = (__bf16)e3;
            }
            sp[mi][0]+=e0; sp[mi][1]+=e1; sp[mi][2]+=e2; sp[mi][3]+=e3;
            float g1c0 = wsm[64], g1c1 = wsm[65];
            #pragma unroll
            for(int j=0;j<10;j++){
                float g = silu_f(Bv[j] + fi*wsm[76+j]);
                g1c0 += g*wsm[44 + j*2 + 0];
                g1c1 += g*wsm[44 + j*2 + 1];
            }
            float c0 = silu_f(g1c0), c1 = silu_f(g1c1);
            wcp[mi][0][0]+=e0*c0; wcp[mi][0][1]+=e0*c1;
            wcp[mi][1][0]+=e1*c0; wcp[mi][1][1]+=e1*c1;
            wcp[mi][2][0]+=e2*c0; wcp[mi][2][1]+=e2*c1;
            wcp[mi][3][0]+=e3*c0; wcp[mi][3][1]+=e3*c1;
        }
    }
    #pragma unroll
    for(int mi=0;mi<4;mi++){
        #pragma unroll
        for(int q=0;q<4;q++){
            sp[mi][q] = wred_sum(sp[mi][q]);
            wcp[mi][q][0] = wred_sum(wcp[mi][q][0]);
            wcp[mi][q][1] = wred_sum(wcp[mi][q][1]);
        }
    }
    if(lane==0){
        int base = 64 + w*48;
        #pragma unroll
        for(int mi=0;mi<4;mi++){
            #pragma unroll
            for(int q=0;q<4;q++){
                scr[base + mi*4 + q] = sp[mi][q];
                scr[base + 16 + (mi*4+q)*2 + 0] = wcp[mi][q][0];
                scr[base + 16 + (mi*4+q)*2 + 1] = wcp[mi][q][1];
            }
        }
    }
    __syncthreads();   // publish e-values + partial sums

    if(tid < 16){      // inv[mq]
        float s = scr[64+0*48+tid] + scr[64+1*48+tid] + scr[64+2*48+tid] + scr[64+3*48+tid];
        scr[256+tid] = 1.0f/s;
    }
    if(tid >= 32 && tid < 64){   // WCs -> PTlb[m][768+q*2+p] (different wave than inv writers is fine)
        int j = tid - 32;
        int mi = j>>3, qp = j&7, q = qp>>1;
        float num = scr[64+0*48+16+(mi*4+q)*2+(qp&1)] + scr[64+1*48+16+(mi*4+q)*2+(qp&1)]
                  + scr[64+2*48+16+(mi*4+q)*2+(qp&1)] + scr[64+3*48+16+(mi*4+q)*2+(qp&1)];
        float den = scr[64+0*48+mi*4+q] + scr[64+1*48+mi*4+q]
                  + scr[64+2*48+mi*4+q] + scr[64+3*48+mi*4+q];
        PTlb[mi*832 + ((768+qp) ^ ((mi&7)<<3))] = (__bf16)(num/den);
    }
    __syncthreads();   // publish inv + WCs

    // ---- GEMM1: PT[h][mq] = Hb @ e ----
    int cl = lane & 15, kg = lane >> 4;
    int swzW = (cl&7)<<3;
    f32x4 acc1[3];
    #pragma unroll
    for(int i=0;i<3;i++) acc1[i] = (f32x4){0.f,0.f,0.f,0.f};
    const __bf16* Aptr = Hb + (size_t)(w*48 + cl)*1024 + kg*8;
    const __bf16* wTrow = wT + cl*1024;
    #pragma unroll 2
    for(int ks=0; ks<32; ks++){
        int k0 = ks*32;
        bf16x8 bf = *(const bf16x8*)&wTrow[(k0 + kg*8) ^ swzW];
        #pragma unroll
        for(int i=0;i<3;i++){
            bf16x8 af = *(const bf16x8*)(Aptr + i*16*1024 + k0);
            acc1[i] = __builtin_amdgcn_mfma_f32_16x16x32_bf16(af, bf, acc1[i], 0, 0, 0);
        }
    }
    {
        int mP = cl >> 2, qP = cl & 3;
        float invv = scr[256 + cl];
        int swzP = (mP&7)<<3;
        #pragma unroll
        for(int i=0;i<3;i++){
            int hb = w*48 + i*16 + kg*4;
            #pragma unroll
            for(int r=0;r<4;r++){
                int k = qP*192 + hb + r;
                PTlb[mP*832 + (k ^ swzP)] = (__bf16)(acc1[i][r] * invv);
            }
        }
    }
    __syncthreads();   // PT ready

    // ---- GEMM2: O[c][m] = WfoldT @ PT  (K=800 incl. WC terms + zero pad) ----
    f32x4 acc2[3];
    #pragma unroll
    for(int i=0;i<3;i++) acc2[i] = (f32x4){0.f,0.f,0.f,0.f};
    const __bf16* A2ptr = WfT + (size_t)(w*48 + cl)*800 + kg*8;
    const __bf16* Prow = PTlb + cl*832;
    int swzP2 = (cl&7)<<3;
    #pragma unroll 2
    for(int ks=0; ks<25; ks++){
        int k0 = ks*32;
        bf16x8 bf = *(const bf16x8*)&Prow[(k0 + kg*8) ^ swzP2];
        #pragma unroll
        for(int i=0;i<3;i++){
            bf16x8 af = *(const bf16x8*)(A2ptr + i*16*800 + k0);
            acc2[i] = __builtin_amdgcn_mfma_f32_16x16x32_bf16(af, bf, acc2[i], 0, 0, 0);
        }
    }
    if(cl < 4 && m0 + cl < M){
        #pragma unroll
        for(int i=0;i<3;i++){
            int cb = w*48 + i*16 + kg*4;
            #pragma unroll
            for(int r=0;r<4;r++){
                out[(size_t)(cb+r)*M + m0 + cl] = acc2[i][r] + b2g[cb+r];
            }
        }
    }
    if(tid < 4 && m0 + tid < M) out[(size_t)C*M + m0 + tid] = 0.f;
}

// ---------------- host ----------------
extern "C" void kernel_launch(void* const* d_in, const int* in_sizes, int n_in,
                              void* d_out, int out_size, void* d_ws, size_t ws_size,
                              hipStream_t stream)
{
    const float* H      = (const float*)d_in[0];
    const int*   d      = (const int*)  d_in[1];
    const float* W_in   = (const float*)d_in[3];
    const float* b_in   = (const float*)d_in[4];
    const float* conv_w = (const float*)d_in[5];
    const float* conv_b = (const float*)d_in[6];
    const float* gamma  = (const float*)d_in[7];
    const float* beta   = (const float*)d_in[8];
    const float* wp1    = (const float*)d_in[9];
    const float* bp1    = (const float*)d_in[10];
    const float* wp2    = (const float*)d_in[11];
    const float* bp2    = (const float*)d_in[12];
    const float* wc1    = (const float*)d_in[13];
    const float* bc1    = (const float*)d_in[14];
    const float* wc2    = (const float*)d_in[15];
    const float* bc2    = (const float*)d_in[16];
    const float* W_WH   = (const float*)d_in[17];
    const float* b_WH   = (const float*)d_in[18];
    const float* W_WC   = (const float*)d_in[19];
    const float* b_WC   = (const float*)d_in[20];
    const float* W_out  = (const float*)d_in[21];
    const float* b_out  = (const float*)d_in[22];

    float* out = (float*)d_out;
    int M = out_size / 193;          // out = [192*M] O + [M] ~frame_valid

    // ws layout (float offsets)
    float* ws   = (float*)d_ws;
    float* Sd   = ws;                              // 1024
    float* Ed   = ws + 1024;                       // 1024
    float* A1   = ws + 2048;                       // 1024*12
    float* A2   = ws + 14336;                      // 1024*12
    float* uvp  = ws + 26624;                      // 20 (pad 32)
    float* b2   = ws + 26656;                      // 192
    __bf16* WfT = (__bf16*)(ws + 26848);           // 192*800 bf16 = 76800 floats
    __bf16* Hb  = (__bf16*)(ws + 103648);          // 192*1024 bf16 = 98304 floats
    float* x    = ws + 201952;                     // 1024*192
    float* xf   = ws + 398560;                     // 1024*8    (end 406752 floats ~ 1.63 MB)

    hipLaunchKernelGGL(k_scan,    dim3(1),   dim3(1024), 0, stream, d, Sd, Ed);
    hipLaunchKernelGGL(k_proj_in, dim3(64),  dim3(192),  0, stream, H, W_in, b_in, x);
    hipLaunchKernelGGL(k_conv_ln, dim3(32),  dim3(256),  0, stream, x, conv_w, conv_b, gamma, beta, xf);
    hipLaunchKernelGGL(k_A,       dim3(5),   dim3(256),  0, stream, Sd, Ed, xf, wp1, bp1, wc1, bc1, A1, A2, uvp);
    hipLaunchKernelGGL(k_hb,      dim3(96),  dim3(256),  0, stream, H, Hb);
    hipLaunchKernelGGL(k_fold,    dim3(778), dim3(192),  0, stream, W_WH, W_WC, b_WH, b_WC, W_out, b_out, WfT, b2);
    hipLaunchKernelGGL(k_main,    dim3((M+3)/4), dim3(256), 0, stream,
                       Hb, A1, A2, uvp, wp2, bp2, wc2, bc2, WfT, b2, out, M);
}

// Round 5
// 254.127 us; speedup vs baseline: 1.5881x; 1.5881x over previous
//
#include <hip/hip_runtime.h>
#include <math.h>

#define T 1024
#define C 192
#define LN_EPS 1e-5f

typedef __attribute__((ext_vector_type(4))) float f32x4;
typedef __attribute__((ext_vector_type(8))) __bf16 bf16x8;

__device__ __forceinline__ float silu_f(float x){ return x / (1.0f + __expf(-x)); }
__device__ __forceinline__ float wred_max(float v){
    #pragma unroll
    for(int o=32;o;o>>=1) v = fmaxf(v, __shfl_xor(v,o));
    return v;
}
__device__ __forceinline__ float wred_sum(float v){
    #pragma unroll
    for(int o=32;o;o>>=1) v += __shfl_xor(v,o);
    return v;
}

// ---------------- kernel 0: inclusive scan of durations ----------------
__global__ void k_scan(const int* __restrict__ d, float* __restrict__ Sd, float* __restrict__ Ed){
    __shared__ int s[T];
    int tid = threadIdx.x;
    int v = d[tid];
    s[tid] = v;
    for(int off=1; off<T; off<<=1){
        __syncthreads();
        int add = (tid>=off) ? s[tid-off] : 0;
        __syncthreads();
        s[tid] += add;
    }
    __syncthreads();
    Ed[tid] = (float)s[tid];
    Sd[tid] = (float)(s[tid]-v);
}

// ---------------- kernel 1: x = silu(H^T W_in + b_in) [T][C], 4 t per block ----------------
__global__ void k_proj_in(const float* __restrict__ H, const float* __restrict__ W_in,
                          const float* __restrict__ b_in, float* __restrict__ x){
    __shared__ float Hs[192*4];
    int tid = threadIdx.x;          // 192 threads
    int t0 = blockIdx.x*4;
    for(int idx=tid; idx<768; idx+=192){
        int ci = idx>>2, j = idx&3;
        Hs[idx] = H[ci*T + t0 + j];
    }
    __syncthreads();
    int c = tid;
    float acc[4];
    float bb = b_in[c];
    #pragma unroll
    for(int j=0;j<4;j++) acc[j] = bb;
    for(int ci=0; ci<192; ci++){
        float wv = W_in[ci*C + c];
        float4 h4 = *(const float4*)&Hs[ci*4];
        acc[0] += h4.x*wv; acc[1] += h4.y*wv;
        acc[2] += h4.z*wv; acc[3] += h4.w*wv;
    }
    #pragma unroll
    for(int j=0;j<4;j++) x[(t0+j)*C + c] = silu_f(acc[j]);
}

// ---------------- kernel 2: conv1d(C->8,k3,p1) + LN(8) + SiLU -> xf [T][8] ----------------
__global__ void k_conv_ln(const float* __restrict__ x, const float* __restrict__ conv_w,
                          const float* __restrict__ conv_b, const float* __restrict__ gamma,
                          const float* __restrict__ beta, float* __restrict__ xf){
    __shared__ float xc[32][8];
    int tid = threadIdx.x;          // 256 = 32 t x 8 f
    int tl = tid >> 3, f = tid & 7;
    int t = blockIdx.x*32 + tl;
    float acc = conv_b[f];
    for(int k=0;k<3;k++){
        int tt = t + k - 1;
        if(tt>=0 && tt<T){
            const float* xr = x + tt*C;
            const float* wr = conv_w + f*C*3 + k;   // conv_w[f][c][k]
            for(int c2=0;c2<C;c2++) acc += xr[c2]*wr[c2*3];
        }
    }
    xc[tl][f] = acc;
    __syncthreads();
    float mu=0.f;
    #pragma unroll
    for(int j=0;j<8;j++) mu += xc[tl][j];
    mu *= 0.125f;
    float var=0.f;
    #pragma unroll
    for(int j=0;j<8;j++){ float dd = xc[tl][j]-mu; var += dd*dd; }
    var *= 0.125f;
    float vi = rsqrtf(var + LN_EPS);
    float v = (acc - mu)*vi*gamma[f] + beta[f];
    xf[t*8+f] = silu_f(v);
}

// ---------------- kernel 3: A1/A2 [t][12] = m-independent first-layer preacts; uv ----------------
__global__ void k_A(const float* __restrict__ Sd, const float* __restrict__ Ed,
                    const float* __restrict__ xf,
                    const float* __restrict__ wp1, const float* __restrict__ bp1,
                    const float* __restrict__ wc1, const float* __restrict__ bc1,
                    float* __restrict__ A1, float* __restrict__ A2, float* __restrict__ uv){
    int b = blockIdx.x, tid = threadIdx.x;
    if(b==4){
        if(tid<10){
            uv[tid]    = wp1[tid] - wp1[10+tid];   // u = wp1[0,:]-wp1[1,:]
            uv[10+tid] = wc1[tid] - wc1[10+tid];   // v = wc1[0,:]-wc1[1,:]
        }
        return;
    }
    int t = b*256 + tid;
    float sd = Sd[t], ed = Ed[t];
    float xv[8];
    #pragma unroll
    for(int k=0;k<8;k++) xv[k] = xf[t*8+k];
    #pragma unroll
    for(int j=0;j<10;j++){
        float a1 = bp1[j] - sd*wp1[j] + ed*wp1[10+j];
        float a2 = bc1[j] - sd*wc1[j] + ed*wc1[10+j];
        #pragma unroll
        for(int k=0;k<8;k++){
            a1 += xv[k]*wp1[(2+k)*10+j];
            a2 += xv[k]*wc1[(2+k)*10+j];
        }
        A1[t*12+j] = a1;
        A2[t*12+j] = a2;
    }
    A1[t*12+10]=0.f; A1[t*12+11]=0.f;
    A2[t*12+10]=0.f; A2[t*12+11]=0.f;
}

// ---------------- kernel 4: Hb = bf16(H) [192][1024] ----------------
__global__ void k_hb(const float* __restrict__ H, __bf16* __restrict__ Hb){
    int base = (blockIdx.x*256 + threadIdx.x)*8;
    float4 a = *(const float4*)(H + base);
    float4 b = *(const float4*)(H + base + 4);
    bf16x8 o;
    o[0]=(__bf16)a.x; o[1]=(__bf16)a.y; o[2]=(__bf16)a.z; o[3]=(__bf16)a.w;
    o[4]=(__bf16)b.x; o[5]=(__bf16)b.y; o[6]=(__bf16)b.z; o[7]=(__bf16)b.w;
    *(bf16x8*)(Hb + base) = o;
}

// ---------------- kernel 5: fold W_out -> WfoldT[c][800] bf16, b2 ----------------
__global__ void k_fold(const float* __restrict__ W_WH, const float* __restrict__ W_WC,
                       const float* __restrict__ b_WH, const float* __restrict__ b_WC,
                       const float* __restrict__ W_out, const float* __restrict__ b_out,
                       __bf16* __restrict__ WfT, float* __restrict__ b2){
    int i = blockIdx.x, c = threadIdx.x;     // 192 threads
    if(i < 768){
        float a = 0.f;
        for(int j=0;j<C;j++) a += W_WH[i*C+j]*W_out[j*C+c];
        WfT[c*800 + i] = (__bf16)a;
    } else if(i < 776){
        int r = i-768;
        float a = 0.f;
        for(int j=0;j<C;j++) a += W_WC[r*C+j]*W_out[j*C+c];
        WfT[c*800 + 768 + r] = (__bf16)a;
    } else if(i == 776){
        float a = b_out[c];
        for(int j=0;j<C;j++) a += (b_WH[j]+b_WC[j])*W_out[j*C+c];
        b2[c] = a;
    } else {
        for(int k=c; k<192*24; k+=192){
            int cc = k/24, j = k - (k/24)*24;
            WfT[cc*800 + 776 + j] = (__bf16)0.f;
        }
    }
}

// ---------------- kernel 6: main — 4 frames/block, 256 threads, MFMA pass2+epilogue ----------------
__global__ void __launch_bounds__(256) __attribute__((amdgpu_waves_per_eu(4,4)))
k_main(const __bf16* __restrict__ Hb, const float* __restrict__ A1, const float* __restrict__ A2,
       const float* __restrict__ uv,
       const float* __restrict__ wp2, const float* __restrict__ bp2,
       const float* __restrict__ wc2, const float* __restrict__ bc2,
       const __bf16* __restrict__ WfT, const float* __restrict__ b2g,
       float* __restrict__ out, int M)
{
    // LDS layout: PTlb [4*832] bf16 | wT [16*1024] bf16 | scr 288 f | wsm 96 f  = 40960 B
    __shared__ __align__(16) unsigned char smem[40960];
    __bf16* PTlb = (__bf16*)smem;                       // 6656 B
    __bf16* wT   = (__bf16*)(smem + 6656);              // 32768 B
    float*  scr  = (float*)(smem + 6656 + 32768);       // 288 floats
    float*  wsm  = scr + 288;                           // 96 floats

    int tid = threadIdx.x;
    int w = tid >> 6, lane = tid & 63;
    int m0 = blockIdx.x*4;

    if(tid < 40)      wsm[tid] = wp2[tid];
    else if(tid < 44) wsm[tid] = bp2[tid-40];
    else if(tid < 64) wsm[tid] = wc2[tid-44];
    else if(tid < 66) wsm[tid] = bc2[tid-64];
    else if(tid < 86) wsm[tid] = uv[tid-66];
    if(tid >= 128 && tid < 224){        // zero-pad PTlb[m][776..800)
        int j = tid - 128;
        int mi = j/24, k = 776 + (j - (j/24)*24);
        PTlb[mi*832 + (k ^ ((mi&7)<<3))] = (__bf16)0.f;
    }
    __syncthreads();

    // ---- phase A: logits, track max only ----
    float pmax[4][4];
    #pragma unroll
    for(int mi=0;mi<4;mi++){
        #pragma unroll
        for(int q=0;q<4;q++) pmax[mi][q] = -3.0e38f;
    }
    #pragma unroll 1
    for(int ti=0;ti<4;ti++){
        int t = tid + ti*256;
        float4 a0 = *(const float4*)(A1 + t*12);
        float4 a1 = *(const float4*)(A1 + t*12 + 4);
        float4 a2 = *(const float4*)(A1 + t*12 + 8);
        float Av[10] = {a0.x,a0.y,a0.z,a0.w,a1.x,a1.y,a1.z,a1.w,a2.x,a2.y};
        #pragma unroll
        for(int mi=0;mi<4;mi++){
            float fi = (float)(m0 + 1 + mi);
            float l0=wsm[40], l1=wsm[41], l2=wsm[42], l3=wsm[43];
            #pragma unroll
            for(int j=0;j<10;j++){
                float h = silu_f(Av[j] + fi*wsm[66+j]);
                l0 += h*wsm[j*4+0]; l1 += h*wsm[j*4+1];
                l2 += h*wsm[j*4+2]; l3 += h*wsm[j*4+3];
            }
            pmax[mi][0]=fmaxf(pmax[mi][0],l0); pmax[mi][1]=fmaxf(pmax[mi][1],l1);
            pmax[mi][2]=fmaxf(pmax[mi][2],l2); pmax[mi][3]=fmaxf(pmax[mi][3],l3);
        }
    }
    #pragma unroll
    for(int mi=0;mi<4;mi++){
        #pragma unroll
        for(int q=0;q<4;q++) pmax[mi][q] = wred_max(pmax[mi][q]);
    }
    if(lane==0){
        #pragma unroll
        for(int mi=0;mi<4;mi++){
            #pragma unroll
            for(int q=0;q<4;q++) scr[w*16 + mi*4 + q] = pmax[mi][q];
        }
    }
    __syncthreads();
    float mx[4][4];
    #pragma unroll
    for(int mi=0;mi<4;mi++){
        #pragma unroll
        for(int q=0;q<4;q++){
            float a = fmaxf(scr[0*16+mi*4+q], scr[1*16+mi*4+q]);
            float b = fmaxf(scr[2*16+mi*4+q], scr[3*16+mi*4+q]);
            mx[mi][q] = fmaxf(a,b);
        }
    }

    // ---- phase B: recompute logits, exp -> wT (bf16, swizzled), sums ----
    float sp[4][4];
    #pragma unroll
    for(int mi=0;mi<4;mi++){
        #pragma unroll
        for(int q=0;q<4;q++) sp[mi][q]=0.f;
    }
    #pragma unroll 1
    for(int ti=0;ti<4;ti++){
        int t = tid + ti*256;
        float4 a0 = *(const float4*)(A1 + t*12);
        float4 a1 = *(const float4*)(A1 + t*12 + 4);
        float4 a2 = *(const float4*)(A1 + t*12 + 8);
        float Av[10] = {a0.x,a0.y,a0.z,a0.w,a1.x,a1.y,a1.z,a1.w,a2.x,a2.y};
        #pragma unroll
        for(int mi=0;mi<4;mi++){
            float fi = (float)(m0 + 1 + mi);
            float l0=wsm[40], l1=wsm[41], l2=wsm[42], l3=wsm[43];
            #pragma unroll
            for(int j=0;j<10;j++){
                float h = silu_f(Av[j] + fi*wsm[66+j]);
                l0 += h*wsm[j*4+0]; l1 += h*wsm[j*4+1];
                l2 += h*wsm[j*4+2]; l3 += h*wsm[j*4+3];
            }
            float e0 = __expf(l0 - mx[mi][0]);
            float e1 = __expf(l1 - mx[mi][1]);
            float e2 = __expf(l2 - mx[mi][2]);
            float e3 = __expf(l3 - mx[mi][3]);
            int r0 = mi*4;
            wT[(r0+0)*1024 + (t ^ (((r0+0)&7)<<3))] = (__bf16)e0;
            wT[(r0+1)*1024 + (t ^ (((r0+1)&7)<<3))] = (__bf16)e1;
            wT[(r0+2)*1024 + (t ^ (((r0+2)&7)<<3))] = (__bf16)e2;
            wT[(r0+3)*1024 + (t ^ (((r0+3)&7)<<3))] = (__bf16)e3;
            sp[mi][0]+=e0; sp[mi][1]+=e1; sp[mi][2]+=e2; sp[mi][3]+=e3;
        }
    }
    #pragma unroll
    for(int mi=0;mi<4;mi++){
        #pragma unroll
        for(int q=0;q<4;q++) sp[mi][q] = wred_sum(sp[mi][q]);
    }
    if(lane==0){
        #pragma unroll
        for(int mi=0;mi<4;mi++){
            #pragma unroll
            for(int q=0;q<4;q++) scr[64 + w*48 + mi*4 + q] = sp[mi][q];
        }
    }

    // ---- phase C: content path; e re-read from wT (same-thread columns) ----
    float wcp[4][4][2];
    #pragma unroll
    for(int mi=0;mi<4;mi++){
        #pragma unroll
        for(int q=0;q<4;q++){ wcp[mi][q][0]=0.f; wcp[mi][q][1]=0.f; }
    }
    #pragma unroll 1
    for(int ti=0;ti<4;ti++){
        int t = tid + ti*256;
        float4 b0 = *(const float4*)(A2 + t*12);
        float4 b1 = *(const float4*)(A2 + t*12 + 4);
        float4 b2v = *(const float4*)(A2 + t*12 + 8);
        float Bv[10] = {b0.x,b0.y,b0.z,b0.w,b1.x,b1.y,b1.z,b1.w,b2v.x,b2v.y};
        #pragma unroll
        for(int mi=0;mi<4;mi++){
            float fi = (float)(m0 + 1 + mi);
            float g1c0 = wsm[64], g1c1 = wsm[65];
            #pragma unroll
            for(int j=0;j<10;j++){
                float g = silu_f(Bv[j] + fi*wsm[76+j]);
                g1c0 += g*wsm[44 + j*2 + 0];
                g1c1 += g*wsm[44 + j*2 + 1];
            }
            float c0 = silu_f(g1c0), c1 = silu_f(g1c1);
            int r0 = mi*4;
            float e0 = (float)wT[(r0+0)*1024 + (t ^ (((r0+0)&7)<<3))];
            float e1 = (float)wT[(r0+1)*1024 + (t ^ (((r0+1)&7)<<3))];
            float e2 = (float)wT[(r0+2)*1024 + (t ^ (((r0+2)&7)<<3))];
            float e3 = (float)wT[(r0+3)*1024 + (t ^ (((r0+3)&7)<<3))];
            wcp[mi][0][0]+=e0*c0; wcp[mi][0][1]+=e0*c1;
            wcp[mi][1][0]+=e1*c0; wcp[mi][1][1]+=e1*c1;
            wcp[mi][2][0]+=e2*c0; wcp[mi][2][1]+=e2*c1;
            wcp[mi][3][0]+=e3*c0; wcp[mi][3][1]+=e3*c1;
        }
    }
    #pragma unroll
    for(int mi=0;mi<4;mi++){
        #pragma unroll
        for(int q=0;q<4;q++){
            wcp[mi][q][0] = wred_sum(wcp[mi][q][0]);
            wcp[mi][q][1] = wred_sum(wcp[mi][q][1]);
        }
    }
    if(lane==0){
        int base = 64 + w*48 + 16;
        #pragma unroll
        for(int mi=0;mi<4;mi++){
            #pragma unroll
            for(int q=0;q<4;q++){
                scr[base + (mi*4+q)*2 + 0] = wcp[mi][q][0];
                scr[base + (mi*4+q)*2 + 1] = wcp[mi][q][1];
            }
        }
    }
    __syncthreads();   // publish wT e-values, sums, WC partials

    if(tid < 16){      // inv[mq]
        float s = scr[64+0*48+tid] + scr[64+1*48+tid] + scr[64+2*48+tid] + scr[64+3*48+tid];
        scr[256+tid] = 1.0f/s;
    }
    if(tid >= 32 && tid < 64){   // WCs -> PTlb[m][768+q*2+p]
        int j = tid - 32;
        int mi = j>>3, qp = j&7, q = qp>>1;
        float num = scr[64+0*48+16+(mi*4+q)*2+(qp&1)] + scr[64+1*48+16+(mi*4+q)*2+(qp&1)]
                  + scr[64+2*48+16+(mi*4+q)*2+(qp&1)] + scr[64+3*48+16+(mi*4+q)*2+(qp&1)];
        float den = scr[64+0*48+mi*4+q] + scr[64+1*48+mi*4+q]
                  + scr[64+2*48+mi*4+q] + scr[64+3*48+mi*4+q];
        PTlb[mi*832 + ((768+qp) ^ ((mi&7)<<3))] = (__bf16)(num/den);
    }
    __syncthreads();   // publish inv + WCs

    // ---- GEMM1: PT[h][mq] = Hb @ e ----
    int cl = lane & 15, kg = lane >> 4;
    int swzW = (cl&7)<<3;
    f32x4 acc1[3];
    #pragma unroll
    for(int i=0;i<3;i++) acc1[i] = (f32x4){0.f,0.f,0.f,0.f};
    const __bf16* Aptr = Hb + (size_t)(w*48 + cl)*1024 + kg*8;
    const __bf16* wTrow = wT + cl*1024;
    #pragma unroll 2
    for(int ks=0; ks<32; ks++){
        int k0 = ks*32;
        bf16x8 bf = *(const bf16x8*)&wTrow[(k0 + kg*8) ^ swzW];
        #pragma unroll
        for(int i=0;i<3;i++){
            bf16x8 af = *(const bf16x8*)(Aptr + i*16*1024 + k0);
            acc1[i] = __builtin_amdgcn_mfma_f32_16x16x32_bf16(af, bf, acc1[i], 0, 0, 0);
        }
    }
    {
        int mP = cl >> 2, qP = cl & 3;
        float invv = scr[256 + cl];
        int swzP = (mP&7)<<3;
        #pragma unroll
        for(int i=0;i<3;i++){
            int hb = w*48 + i*16 + kg*4;
            #pragma unroll
            for(int r=0;r<4;r++){
                int k = qP*192 + hb + r;
                PTlb[mP*832 + (k ^ swzP)] = (__bf16)(acc1[i][r] * invv);
            }
        }
    }
    __syncthreads();   // PT ready

    // ---- GEMM2: O[c][m] = WfoldT @ PT  (K=800 incl. WC terms + zero pad) ----
    f32x4 acc2[3];
    #pragma unroll
    for(int i=0;i<3;i++) acc2[i] = (f32x4){0.f,0.f,0.f,0.f};
    const __bf16* A2ptr = WfT + (size_t)(w*48 + cl)*800 + kg*8;
    const __bf16* Prow = PTlb + cl*832;
    int swzP2 = (cl&7)<<3;
    #pragma unroll 2
    for(int ks=0; ks<25; ks++){
        int k0 = ks*32;
        bf16x8 bf = *(const bf16x8*)&Prow[(k0 + kg*8) ^ swzP2];
        #pragma unroll
        for(int i=0;i<3;i++){
            bf16x8 af = *(const bf16x8*)(A2ptr + i*16*800 + k0);
            acc2[i] = __builtin_amdgcn_mfma_f32_16x16x32_bf16(af, bf, acc2[i], 0, 0, 0);
        }
    }
    if(cl < 4 && m0 + cl < M){
        #pragma unroll
        for(int i=0;i<3;i++){
            int cb = w*48 + i*16 + kg*4;
            #pragma unroll
            for(int r=0;r<4;r++){
                out[(size_t)(cb+r)*M + m0 + cl] = acc2[i][r] + b2g[cb+r];
            }
        }
    }
    if(tid < 4 && m0 + tid < M) out[(size_t)C*M + m0 + tid] = 0.f;
}

// ---------------- host ----------------
extern "C" void kernel_launch(void* const* d_in, const int* in_sizes, int n_in,
                              void* d_out, int out_size, void* d_ws, size_t ws_size,
                              hipStream_t stream)
{
    const float* H      = (const float*)d_in[0];
    const int*   d      = (const int*)  d_in[1];
    const float* W_in   = (const float*)d_in[3];
    const float* b_in   = (const float*)d_in[4];
    const float* conv_w = (const float*)d_in[5];
    const float* conv_b = (const float*)d_in[6];
    const float* gamma  = (const float*)d_in[7];
    const float* beta   = (const float*)d_in[8];
    const float* wp1    = (const float*)d_in[9];
    const float* bp1    = (const float*)d_in[10];
    const float* wp2    = (const float*)d_in[11];
    const float* bp2    = (const float*)d_in[12];
    const float* wc1    = (const float*)d_in[13];
    const float* bc1    = (const float*)d_in[14];
    const float* wc2    = (const float*)d_in[15];
    const float* bc2    = (const float*)d_in[16];
    const float* W_WH   = (const float*)d_in[17];
    const float* b_WH   = (const float*)d_in[18];
    const float* W_WC   = (const float*)d_in[19];
    const float* b_WC   = (const float*)d_in[20];
    const float* W_out  = (const float*)d_in[21];
    const float* b_out  = (const float*)d_in[22];

    float* out = (float*)d_out;
    int M = out_size / 193;          // out = [192*M] O + [M] ~frame_valid

    // ws layout (float offsets)
    float* ws   = (float*)d_ws;
    float* Sd   = ws;                              // 1024
    float* Ed   = ws + 1024;                       // 1024
    float* A1   = ws + 2048;                       // 1024*12
    float* A2   = ws + 14336;                      // 1024*12
    float* uvp  = ws + 26624;                      // 20 (pad 32)
    float* b2   = ws + 26656;                      // 192
    __bf16* WfT = (__bf16*)(ws + 26848);           // 192*800 bf16 = 76800 floats
    __bf16* Hb  = (__bf16*)(ws + 103648);          // 192*1024 bf16 = 98304 floats
    float* x    = ws + 201952;                     // 1024*192
    float* xf   = ws + 398560;                     // 1024*8    (end 406752 floats ~ 1.63 MB)

    hipLaunchKernelGGL(k_scan,    dim3(1),   dim3(1024), 0, stream, d, Sd, Ed);
    hipLaunchKernelGGL(k_proj_in, dim3(256), dim3(192),  0, stream, H, W_in, b_in, x);
    hipLaunchKernelGGL(k_conv_ln, dim3(32),  dim3(256),  0, stream, x, conv_w, conv_b, gamma, beta, xf);
    hipLaunchKernelGGL(k_A,       dim3(5),   dim3(256),  0, stream, Sd, Ed, xf, wp1, bp1, wc1, bc1, A1, A2, uvp);
    hipLaunchKernelGGL(k_hb,      dim3(96),  dim3(256),  0, stream, H, Hb);
    hipLaunchKernelGGL(k_fold,    dim3(778), dim3(192),  0, stream, W_WH, W_WC, b_WH, b_WC, W_out, b_out, WfT, b2);
    hipLaunchKernelGGL(k_main,    dim3((M+3)/4), dim3(256), 0, stream,
                       Hb, A1, A2, uvp, wp2, bp2, wc2, bc2, WfT, b2, out, M);
}

// Round 6
// 192.249 us; speedup vs baseline: 2.0993x; 1.3219x over previous
//
#include <hip/hip_runtime.h>
#include <math.h>

#define T 1024
#define C 192
#define LN_EPS 1e-5f

typedef __attribute__((ext_vector_type(4))) float f32x4;
typedef __attribute__((ext_vector_type(8))) __bf16 bf16x8;

__device__ __forceinline__ float silu_f(float x){
    return x * __builtin_amdgcn_rcpf(1.0f + __expf(-x));
}
__device__ __forceinline__ float wred_max(float v){
    #pragma unroll
    for(int o=32;o;o>>=1) v = fmaxf(v, __shfl_xor(v,o));
    return v;
}
__device__ __forceinline__ float wred_sum(float v){
    #pragma unroll
    for(int o=32;o;o>>=1) v += __shfl_xor(v,o);
    return v;
}

// ---------------- kernel 0: inclusive scan of durations ----------------
__global__ void k_scan(const int* __restrict__ d, float* __restrict__ Sd, float* __restrict__ Ed){
    __shared__ int s[T];
    int tid = threadIdx.x;
    int v = d[tid];
    s[tid] = v;
    for(int off=1; off<T; off<<=1){
        __syncthreads();
        int add = (tid>=off) ? s[tid-off] : 0;
        __syncthreads();
        s[tid] += add;
    }
    __syncthreads();
    Ed[tid] = (float)s[tid];
    Sd[tid] = (float)(s[tid]-v);
}

// ---------------- kernel 1: x = silu(H^T W_in + b_in) [T][C], 4 t per block ----------------
__global__ void k_proj_in(const float* __restrict__ H, const float* __restrict__ W_in,
                          const float* __restrict__ b_in, float* __restrict__ x){
    __shared__ float Hs[192*4];
    int tid = threadIdx.x;          // 192 threads
    int t0 = blockIdx.x*4;
    for(int idx=tid; idx<768; idx+=192){
        int ci = idx>>2, j = idx&3;
        Hs[idx] = H[ci*T + t0 + j];
    }
    __syncthreads();
    int c = tid;
    float acc[4];
    float bb = b_in[c];
    #pragma unroll
    for(int j=0;j<4;j++) acc[j] = bb;
    for(int ci=0; ci<192; ci++){
        float wv = W_in[ci*C + c];
        float4 h4 = *(const float4*)&Hs[ci*4];
        acc[0] += h4.x*wv; acc[1] += h4.y*wv;
        acc[2] += h4.z*wv; acc[3] += h4.w*wv;
    }
    #pragma unroll
    for(int j=0;j<4;j++) x[(t0+j)*C + c] = silu_f(acc[j]);
}

// ---------------- kernel 2: conv1d(C->8,k3,p1) + LN(8) + SiLU -> xf [T][8], 16t x 8f x 2cc ----------------
__global__ void k_conv_ln(const float* __restrict__ x, const float* __restrict__ conv_w,
                          const float* __restrict__ conv_b, const float* __restrict__ gamma,
                          const float* __restrict__ beta, float* __restrict__ xf){
    __shared__ float part[16][8][2];
    __shared__ float xcv[16][8];
    int tid = threadIdx.x;          // 256 = 16 t x 8 f x 2 cc
    int cc = tid & 1, f = (tid>>1)&7, tl = tid>>4;
    int t = blockIdx.x*16 + tl;
    float acc = 0.f;
    for(int k=0;k<3;k++){
        int tt = t + k - 1;
        if(tt>=0 && tt<T){
            const float* xr = x + tt*C + cc*96;
            const float* wr = conv_w + f*C*3 + k + cc*96*3;
            for(int c2=0;c2<96;c2++) acc += xr[c2]*wr[c2*3];
        }
    }
    part[tl][f][cc] = acc;
    __syncthreads();
    if(cc==0){
        xcv[tl][f] = part[tl][f][0] + part[tl][f][1] + conv_b[f];
    }
    __syncthreads();
    if(cc==0){
        float a = xcv[tl][f];
        float mu=0.f;
        #pragma unroll
        for(int j=0;j<8;j++) mu += xcv[tl][j];
        mu *= 0.125f;
        float var=0.f;
        #pragma unroll
        for(int j=0;j<8;j++){ float dd = xcv[tl][j]-mu; var += dd*dd; }
        var *= 0.125f;
        float vi = rsqrtf(var + LN_EPS);
        float v = (a - mu)*vi*gamma[f] + beta[f];
        xf[t*8+f] = silu_f(v);
    }
}

// ---------------- kernel 3: A1/A2 [t][12] = m-independent first-layer preacts; uv ----------------
__global__ void k_A(const float* __restrict__ Sd, const float* __restrict__ Ed,
                    const float* __restrict__ xf,
                    const float* __restrict__ wp1, const float* __restrict__ bp1,
                    const float* __restrict__ wc1, const float* __restrict__ bc1,
                    float* __restrict__ A1, float* __restrict__ A2, float* __restrict__ uv){
    int b = blockIdx.x, tid = threadIdx.x;
    if(b==4){
        if(tid<10){
            uv[tid]    = wp1[tid] - wp1[10+tid];   // u = wp1[0,:]-wp1[1,:]
            uv[10+tid] = wc1[tid] - wc1[10+tid];   // v = wc1[0,:]-wc1[1,:]
        }
        return;
    }
    int t = b*256 + tid;
    float sd = Sd[t], ed = Ed[t];
    float xv[8];
    #pragma unroll
    for(int k=0;k<8;k++) xv[k] = xf[t*8+k];
    #pragma unroll
    for(int j=0;j<10;j++){
        float a1 = bp1[j] - sd*wp1[j] + ed*wp1[10+j];
        float a2 = bc1[j] - sd*wc1[j] + ed*wc1[10+j];
        #pragma unroll
        for(int k=0;k<8;k++){
            a1 += xv[k]*wp1[(2+k)*10+j];
            a2 += xv[k]*wc1[(2+k)*10+j];
        }
        A1[t*12+j] = a1;
        A2[t*12+j] = a2;
    }
    A1[t*12+10]=0.f; A1[t*12+11]=0.f;
    A2[t*12+10]=0.f; A2[t*12+11]=0.f;
}

// ---------------- kernel 4: Hb = bf16(H) [192][1024] ----------------
__global__ void k_hb(const float* __restrict__ H, __bf16* __restrict__ Hb){
    int base = (blockIdx.x*256 + threadIdx.x)*8;
    float4 a = *(const float4*)(H + base);
    float4 b = *(const float4*)(H + base + 4);
    bf16x8 o;
    o[0]=(__bf16)a.x; o[1]=(__bf16)a.y; o[2]=(__bf16)a.z; o[3]=(__bf16)a.w;
    o[4]=(__bf16)b.x; o[5]=(__bf16)b.y; o[6]=(__bf16)b.z; o[7]=(__bf16)b.w;
    *(bf16x8*)(Hb + base) = o;
}

// ---------------- kernel 5: fold W_out -> WfoldT[c][800] bf16, b2 ----------------
__global__ void k_fold(const float* __restrict__ W_WH, const float* __restrict__ W_WC,
                       const float* __restrict__ b_WH, const float* __restrict__ b_WC,
                       const float* __restrict__ W_out, const float* __restrict__ b_out,
                       __bf16* __restrict__ WfT, float* __restrict__ b2){
    int i = blockIdx.x, c = threadIdx.x;     // 192 threads
    if(i < 768){
        float a = 0.f;
        for(int j=0;j<C;j++) a += W_WH[i*C+j]*W_out[j*C+c];
        WfT[c*800 + i] = (__bf16)a;
    } else if(i < 776){
        int r = i-768;
        float a = 0.f;
        for(int j=0;j<C;j++) a += W_WC[r*C+j]*W_out[j*C+c];
        WfT[c*800 + 768 + r] = (__bf16)a;
    } else if(i == 776){
        float a = b_out[c];
        for(int j=0;j<C;j++) a += (b_WH[j]+b_WC[j])*W_out[j*C+c];
        b2[c] = a;
    } else {
        for(int k=c; k<192*24; k+=192){
            int cc = k/24, j = k - (k/24)*24;
            WfT[cc*800 + 776 + j] = (__bf16)0.f;
        }
    }
}

// ---------------- kernel 6: main — 4 frames/block, 256 threads, fused per-mi softmax + MFMA ----------------
__global__ void __launch_bounds__(256) __attribute__((amdgpu_waves_per_eu(4,4)))
k_main(const __bf16* __restrict__ Hb, const float* __restrict__ A1, const float* __restrict__ A2,
       const float* __restrict__ uv,
       const float* __restrict__ wp2, const float* __restrict__ bp2,
       const float* __restrict__ wc2, const float* __restrict__ bc2,
       const __bf16* __restrict__ WfT, const float* __restrict__ b2g,
       float* __restrict__ out, int M)
{
    // LDS layout: PTlb [4*832] bf16 | wT [16*1024] bf16 | scr 288 f | wsm 96 f  = 40960 B
    __shared__ __align__(16) unsigned char smem[40960];
    __bf16* PTlb = (__bf16*)smem;                       // 6656 B
    __bf16* wT   = (__bf16*)(smem + 6656);              // 32768 B
    float*  scr  = (float*)(smem + 6656 + 32768);       // 288 floats
    float*  wsm  = scr + 288;                           // 96 floats

    int tid = threadIdx.x;
    int w = tid >> 6, lane = tid & 63;
    int m0 = blockIdx.x*4;

    if(tid < 40)      wsm[tid] = wp2[tid];
    else if(tid < 44) wsm[tid] = bp2[tid-40];
    else if(tid < 64) wsm[tid] = wc2[tid-44];
    else if(tid < 66) wsm[tid] = bc2[tid-64];
    else if(tid < 86) wsm[tid] = uv[tid-66];
    if(tid < 224){                      // zero-pad PTlb[m][776..832) (XOR'd reads can hit [800,832))
        int mi = tid/56, k = 776 + tid - (tid/56)*56;
        PTlb[mi*832 + (k ^ (mi<<4))] = (__bf16)0.f;
    }
    __syncthreads();

    // ---- fused per-frame softmax: logits once, kept in regs across max barrier ----
    // scr layout: [0,64) per-mi per-wave max (mi*16 + w*4 + q)
    //             [64,256) per-mi per-wave sums (64 + mi*48 + w*12 + {q | 4 + q*2 + p})
    //             [256,272) inv[mi*4+q]
    for(int mi=0; mi<4; mi++){
        float fi = (float)(m0 + 1 + mi);
        float l[4][4];
        #pragma unroll 1
        for(int ti=0; ti<4; ti++){
            int t = tid + ti*256;
            float4 a0 = *(const float4*)(A1 + t*12);
            float4 a1 = *(const float4*)(A1 + t*12 + 4);
            float4 a2v = *(const float4*)(A1 + t*12 + 8);
            float Av[10] = {a0.x,a0.y,a0.z,a0.w,a1.x,a1.y,a1.z,a1.w,a2v.x,a2v.y};
            float l0=wsm[40], l1=wsm[41], l2=wsm[42], l3=wsm[43];
            #pragma unroll
            for(int j=0;j<10;j++){
                float h = silu_f(Av[j] + fi*wsm[66+j]);
                l0 += h*wsm[j*4+0]; l1 += h*wsm[j*4+1];
                l2 += h*wsm[j*4+2]; l3 += h*wsm[j*4+3];
            }
            l[ti][0]=l0; l[ti][1]=l1; l[ti][2]=l2; l[ti][3]=l3;
        }
        #pragma unroll
        for(int q=0;q<4;q++){
            float lm = fmaxf(fmaxf(l[0][q],l[1][q]), fmaxf(l[2][q],l[3][q]));
            lm = wred_max(lm);
            if(lane==0) scr[mi*16 + w*4 + q] = lm;
        }
        __syncthreads();
        float mxq[4];
        #pragma unroll
        for(int q=0;q<4;q++){
            float a = fmaxf(scr[mi*16+0*4+q], scr[mi*16+1*4+q]);
            float b = fmaxf(scr[mi*16+2*4+q], scr[mi*16+3*4+q]);
            mxq[q] = fmaxf(a,b);
        }
        // exp in place + store bf16 to wT + sums
        float sp4[4] = {0.f,0.f,0.f,0.f};
        #pragma unroll
        for(int ti=0;ti<4;ti++){
            int t = tid + ti*256;
            #pragma unroll
            for(int q=0;q<4;q++){
                float e = __expf(l[ti][q] - mxq[q]);
                l[ti][q] = e;
                int row = mi*4+q;
                wT[row*1024 + (t ^ ((row&7)<<3))] = (__bf16)e;
                sp4[q] += e;
            }
        }
        // C-path: cm values + weighted sums (e still in regs)
        float wcp2[4][2];
        #pragma unroll
        for(int q=0;q<4;q++){ wcp2[q][0]=0.f; wcp2[q][1]=0.f; }
        #pragma unroll 1
        for(int ti=0;ti<4;ti++){
            int t = tid + ti*256;
            float4 b0 = *(const float4*)(A2 + t*12);
            float4 b1 = *(const float4*)(A2 + t*12 + 4);
            float4 b2v = *(const float4*)(A2 + t*12 + 8);
            float Bv[10] = {b0.x,b0.y,b0.z,b0.w,b1.x,b1.y,b1.z,b1.w,b2v.x,b2v.y};
            float g1c0 = wsm[64], g1c1 = wsm[65];
            #pragma unroll
            for(int j=0;j<10;j++){
                float g = silu_f(Bv[j] + fi*wsm[76+j]);
                g1c0 += g*wsm[44 + j*2 + 0];
                g1c1 += g*wsm[44 + j*2 + 1];
            }
            float c0 = silu_f(g1c0), c1 = silu_f(g1c1);
            #pragma unroll
            for(int q=0;q<4;q++){
                wcp2[q][0] += l[ti][q]*c0;
                wcp2[q][1] += l[ti][q]*c1;
            }
        }
        #pragma unroll
        for(int q=0;q<4;q++){
            sp4[q] = wred_sum(sp4[q]);
            wcp2[q][0] = wred_sum(wcp2[q][0]);
            wcp2[q][1] = wred_sum(wcp2[q][1]);
        }
        if(lane==0){
            int base = 64 + mi*48 + w*12;
            #pragma unroll
            for(int q=0;q<4;q++){
                scr[base + q] = sp4[q];
                scr[base + 4 + q*2 + 0] = wcp2[q][0];
                scr[base + 4 + q*2 + 1] = wcp2[q][1];
            }
        }
    }
    __syncthreads();   // publish wT e-values + all partial sums

    if(tid < 16){      // inv[mq],  tid = mi*4+q
        int mi = tid>>2, q = tid&3;
        float s = scr[64+mi*48+0*12+q] + scr[64+mi*48+1*12+q]
                + scr[64+mi*48+2*12+q] + scr[64+mi*48+3*12+q];
        scr[256+tid] = 1.0f/s;
    }
    if(tid >= 32 && tid < 64){   // WCs -> PTlb[m][768+q*2+p]
        int j = tid - 32;
        int mi = j>>3, qp = j&7, q = qp>>1, p = qp&1;
        float num = scr[64+mi*48+0*12+4+q*2+p] + scr[64+mi*48+1*12+4+q*2+p]
                  + scr[64+mi*48+2*12+4+q*2+p] + scr[64+mi*48+3*12+4+q*2+p];
        float den = scr[64+mi*48+0*12+q] + scr[64+mi*48+1*12+q]
                  + scr[64+mi*48+2*12+q] + scr[64+mi*48+3*12+q];
        PTlb[mi*832 + ((768+qp) ^ (mi<<4))] = (__bf16)(num/den);
    }
    __syncthreads();   // publish inv + WCs

    // ---- GEMM1: PT[h][mq] = Hb @ e ----
    int cl = lane & 15, kg = lane >> 4;
    int swzW = (cl&7)<<3;
    f32x4 acc1[3];
    #pragma unroll
    for(int i=0;i<3;i++) acc1[i] = (f32x4){0.f,0.f,0.f,0.f};
    const __bf16* Aptr = Hb + (size_t)(w*48 + cl)*1024 + kg*8;
    const __bf16* wTrow = wT + cl*1024;
    #pragma unroll 2
    for(int ks=0; ks<32; ks++){
        int k0 = ks*32;
        bf16x8 bf = *(const bf16x8*)&wTrow[(k0 + kg*8) ^ swzW];
        #pragma unroll
        for(int i=0;i<3;i++){
            bf16x8 af = *(const bf16x8*)(Aptr + i*16*1024 + k0);
            acc1[i] = __builtin_amdgcn_mfma_f32_16x16x32_bf16(af, bf, acc1[i], 0, 0, 0);
        }
    }
    {
        int mP = cl >> 2, qP = cl & 3;
        float invv = scr[256 + cl];
        int swzP = mP<<4;
        #pragma unroll
        for(int i=0;i<3;i++){
            int hb = w*48 + i*16 + kg*4;
            #pragma unroll
            for(int r=0;r<4;r++){
                int k = qP*192 + hb + r;
                PTlb[mP*832 + (k ^ swzP)] = (__bf16)(acc1[i][r] * invv);
            }
        }
    }
    __syncthreads();   // PT ready

    // ---- GEMM2: O[c][m] = WfoldT @ PT  (K=800 incl. WC terms + zero pad) ----
    f32x4 acc2[3];
    #pragma unroll
    for(int i=0;i<3;i++) acc2[i] = (f32x4){0.f,0.f,0.f,0.f};
    const __bf16* A2ptr = WfT + (size_t)(w*48 + cl)*800 + kg*8;
    const __bf16* Prow = PTlb + cl*832;
    int swzP2 = (cl&3)<<4;
    #pragma unroll 2
    for(int ks=0; ks<25; ks++){
        int k0 = ks*32;
        bf16x8 bf = *(const bf16x8*)&Prow[(k0 + kg*8) ^ swzP2];
        #pragma unroll
        for(int i=0;i<3;i++){
            bf16x8 af = *(const bf16x8*)(A2ptr + i*16*800 + k0);
            acc2[i] = __builtin_amdgcn_mfma_f32_16x16x32_bf16(af, bf, acc2[i], 0, 0, 0);
        }
    }
    if(cl < 4 && m0 + cl < M){
        #pragma unroll
        for(int i=0;i<3;i++){
            int cb = w*48 + i*16 + kg*4;
            #pragma unroll
            for(int r=0;r<4;r++){
                out[(size_t)(cb+r)*M + m0 + cl] = acc2[i][r] + b2g[cb+r];
            }
        }
    }
    if(tid < 4 && m0 + tid < M) out[(size_t)C*M + m0 + tid] = 0.f;
}

// ---------------- host ----------------
extern "C" void kernel_launch(void* const* d_in, const int* in_sizes, int n_in,
                              void* d_out, int out_size, void* d_ws, size_t ws_size,
                              hipStream_t stream)
{
    const float* H      = (const float*)d_in[0];
    const int*   d      = (const int*)  d_in[1];
    const float* W_in   = (const float*)d_in[3];
    const float* b_in   = (const float*)d_in[4];
    const float* conv_w = (const float*)d_in[5];
    const float* conv_b = (const float*)d_in[6];
    const float* gamma  = (const float*)d_in[7];
    const float* beta   = (const float*)d_in[8];
    const float* wp1    = (const float*)d_in[9];
    const float* bp1    = (const float*)d_in[10];
    const float* wp2    = (const float*)d_in[11];
    const float* bp2    = (const float*)d_in[12];
    const float* wc1    = (const float*)d_in[13];
    const float* bc1    = (const float*)d_in[14];
    const float* wc2    = (const float*)d_in[15];
    const float* bc2    = (const float*)d_in[16];
    const float* W_WH   = (const float*)d_in[17];
    const float* b_WH   = (const float*)d_in[18];
    const float* W_WC   = (const float*)d_in[19];
    const float* b_WC   = (const float*)d_in[20];
    const float* W_out  = (const float*)d_in[21];
    const float* b_out  = (const float*)d_in[22];

    float* out = (float*)d_out;
    int M = out_size / 193;          // out = [192*M] O + [M] ~frame_valid

    // ws layout (float offsets)
    float* ws   = (float*)d_ws;
    float* Sd   = ws;                              // 1024
    float* Ed   = ws + 1024;                       // 1024
    float* A1   = ws + 2048;                       // 1024*12
    float* A2   = ws + 14336;                      // 1024*12
    float* uvp  = ws + 26624;                      // 20 (pad 32)
    float* b2   = ws + 26656;                      // 192
    __bf16* WfT = (__bf16*)(ws + 26848);           // 192*800 bf16 = 76800 floats
    __bf16* Hb  = (__bf16*)(ws + 103648);          // 192*1024 bf16 = 98304 floats
    float* x    = ws + 201952;                     // 1024*192
    float* xf   = ws + 398560;                     // 1024*8    (end 406752 floats ~ 1.63 MB)

    hipLaunchKernelGGL(k_scan,    dim3(1),   dim3(1024), 0, stream, d, Sd, Ed);
    hipLaunchKernelGGL(k_proj_in, dim3(256), dim3(192),  0, stream, H, W_in, b_in, x);
    hipLaunchKernelGGL(k_conv_ln, dim3(64),  dim3(256),  0, stream, x, conv_w, conv_b, gamma, beta, xf);
    hipLaunchKernelGGL(k_A,       dim3(5),   dim3(256),  0, stream, Sd, Ed, xf, wp1, bp1, wc1, bc1, A1, A2, uvp);
    hipLaunchKernelGGL(k_hb,      dim3(96),  dim3(256),  0, stream, H, Hb);
    hipLaunchKernelGGL(k_fold,    dim3(778), dim3(192),  0, stream, W_WH, W_WC, b_WH, b_WC, W_out, b_out, WfT, b2);
    hipLaunchKernelGGL(k_main,    dim3((M+3)/4), dim3(256), 0, stream,
                       Hb, A1, A2, uvp, wp2, bp2, wc2, bc2, WfT, b2, out, M);
}